// Round 1
// baseline (183.457 us; speedup 1.0000x reference)
//
#include <hip/hip_runtime.h>

#define LOG2E 1.4426950408889634f

typedef __attribute__((ext_vector_type(4))) float f32x4;
typedef __attribute__((ext_vector_type(4))) short s16x4;
typedef __attribute__((ext_vector_type(4))) __bf16 bf16x4;

// Causal self-attention forward, B=2 S=2048 H=16 D=64, fp32 in/out.
// One wave per 16 q-rows. S^T = K*Q^T via mfma so P registers feed the
// PV mfma (OT = V^T * P) with zero cross-lane traffic; softmax stats are
// lane-local (q = lane&15 in both layouts).
__global__ __launch_bounds__(256) void attn_fwd(
    const float* __restrict__ Qg, const float* __restrict__ Kg,
    const float* __restrict__ Vg, float* __restrict__ Og)
{
  constexpr int S = 2048, H = 16, D = 64, HS = H * D;  // HS = 1024 elems
  const int tid  = threadIdx.x;
  const int lane = tid & 63;
  const int lm   = lane & 15;   // q-column (and d-row for PV out)
  const int g    = lane >> 4;   // 4-lane group
  const int w    = tid >> 6;    // wave in block

  const int bh = blockIdx.x;    // 0..31
  const int b  = bh >> 4;
  const int h  = bh & 15;
  // heavy-first: largest q-tiles dispatched first (causal imbalance)
  const int t  = ((gridDim.y - 1 - blockIdx.y) << 2) | w;  // q-tile 0..127
  const int qb = t << 4;

  const size_t base = (size_t)b * S * HS + (size_t)h * D;

  // ---- Q fragments (B operand of S^T mfma), pre-scaled by 0.125*log2(e)
  s16x4 qf[4];
  {
    const float* qp = Qg + base + (size_t)(qb + lm) * HS + g * 4;
    const float qs = 0.125f * LOG2E;
#pragma unroll
    for (int c = 0; c < 4; ++c) {
      f32x4 qv = *(const f32x4*)(qp + c * 16);
      bf16x4 bv;
#pragma unroll
      for (int j = 0; j < 4; ++j) bv[j] = (__bf16)(qv[j] * qs);
      qf[c] = __builtin_bit_cast(s16x4, bv);
    }
  }

  f32x4 oacc[4] = {{0,0,0,0},{0,0,0,0},{0,0,0,0},{0,0,0,0}};
  float m = -1e30f, lsum = 0.0f;

  const float* kp = Kg + base + (size_t)lm * HS + g * 4;       // K row = key
  const float* vp = Vg + base + (size_t)(g * 4) * HS + lm;     // V^T frag

  for (int kt = 0; kt <= t; ++kt) {
    // ---- S^T tile: 16 keys x 16 q, K is A operand, Q is B operand
    const float* kpp = kp + (size_t)(kt << 4) * HS;
    f32x4 st = {0, 0, 0, 0};
#pragma unroll
    for (int c = 0; c < 4; ++c) {
      f32x4 kv = *(const f32x4*)(kpp + c * 16);
      bf16x4 bv;
#pragma unroll
      for (int j = 0; j < 4; ++j) bv[j] = (__bf16)kv[j];
      st = __builtin_amdgcn_mfma_f32_16x16x16bf16_1k(
               __builtin_bit_cast(s16x4, bv), qf[c], st, 0, 0, 0);
    }
    // st[r] = score(key = kb + 4g + r, q = qb + lm), scaled by 0.125*log2e

    if (kt == t) {  // diagonal tile: causal mask (key > q -> -inf)
#pragma unroll
      for (int r = 0; r < 4; ++r)
        if (g * 4 + r > lm) st[r] = -1e30f;
    }

    // ---- online softmax; all stats indexed by q = lane&15 (lane-local)
    float tmax = fmaxf(fmaxf(st[0], st[1]), fmaxf(st[2], st[3]));
    tmax = fmaxf(tmax, __shfl_xor(tmax, 16));
    tmax = fmaxf(tmax, __shfl_xor(tmax, 32));
    const float mnew = fmaxf(m, tmax);
    const float fsc  = exp2f(m - mnew);
    f32x4 p;
#pragma unroll
    for (int r = 0; r < 4; ++r) p[r] = exp2f(st[r] - mnew);
    float tsum = (p[0] + p[1]) + (p[2] + p[3]);
    tsum += __shfl_xor(tsum, 16);
    tsum += __shfl_xor(tsum, 32);
    lsum = lsum * fsc + tsum;
    m = mnew;
#pragma unroll
    for (int nb = 0; nb < 4; ++nb)
#pragma unroll
      for (int r = 0; r < 4; ++r) oacc[nb][r] *= fsc;

    // ---- P fragment: exactly the B operand of the PV mfma (k=key=4g+r)
    bf16x4 pb;
#pragma unroll
    for (int r = 0; r < 4; ++r) pb[r] = (__bf16)p[r];
    const s16x4 pf = __builtin_bit_cast(s16x4, pb);

    // ---- PV: OT[d][q] += V^T * P, 4 d-blocks of 16
    const float* vpp = vp + (size_t)(kt << 4) * HS;
#pragma unroll
    for (int nb = 0; nb < 4; ++nb) {
      bf16x4 vv;
#pragma unroll
      for (int j = 0; j < 4; ++j)
        vv[j] = (__bf16)vpp[(size_t)j * HS + nb * 16];
      oacc[nb] = __builtin_amdgcn_mfma_f32_16x16x16bf16_1k(
                     __builtin_bit_cast(s16x4, vv), pf, oacc[nb], 0, 0, 0);
    }
  }

  // ---- normalize and store: lane holds out[q=qb+lm][d=16nb+4g+r]
  const float inv = 1.0f / lsum;
  float* op = Og + base + (size_t)(qb + lm) * HS + g * 4;
#pragma unroll
  for (int nb = 0; nb < 4; ++nb) {
    f32x4 o = oacc[nb];
#pragma unroll
    for (int r = 0; r < 4; ++r) o[r] *= inv;
    *(f32x4*)(op + nb * 16) = o;
  }
}

extern "C" void kernel_launch(void* const* d_in, const int* in_sizes, int n_in,
                              void* d_out, int out_size, void* d_ws, size_t ws_size,
                              hipStream_t stream) {
  const float* q = (const float*)d_in[0];
  const float* k = (const float*)d_in[1];
  const float* v = (const float*)d_in[2];
  float* o = (float*)d_out;
  dim3 grid(32, 32);   // x = b*h, y = q-tile group (reversed => heavy first)
  dim3 block(256);     // 4 independent waves, one 16-row q-tile each
  attn_fwd<<<grid, block, 0, stream>>>(q, k, v, o);
}